// Round 2
// baseline (2044.954 us; speedup 1.0000x reference)
//
#include <hip/hip_runtime.h>
#include <math.h>

#define Bb 64
#define Tt 20
#define Vv 20000
#define Ee 512
#define Hh 512
#define Ll 49

// ---------------------------------------------------------------------------
// features (B,512,1,7,7) -> f2 (B,49,512)   f2[b,l,c] = feat[b,c,0,l]
// Per block: one b, half the channels (256) staged in LDS, transposed write.
__global__ __launch_bounds__(256) void transpose_features_k(
    const float* __restrict__ feat, float* __restrict__ f2) {
  __shared__ float lds[256 * 49];
  const int b = blockIdx.x >> 1, half = blockIdx.x & 1;
  const int c0 = half * 256;
  const float* src = feat + ((size_t)b * 512 + c0) * 49;
  for (int i = threadIdx.x; i < 256 * 49; i += 256) lds[i] = src[i];
  __syncthreads();
  // stride-49 LDS reads: gcd(49,32)=1 -> conflict-free; writes coalesced
  for (int l = 0; l < 49; ++l)
    f2[((size_t)b * 49 + l) * 512 + c0 + threadIdx.x] = lds[threadIdx.x * 49 + l];
}

// ---------------------------------------------------------------------------
// Generic NT GEMM: C[m,n] = sum_k A[m*lda+k] * W[n*ldw+k]  (+bias[n]) (+add[m*ldadd+n])
// optional mask: if lengths != nullptr, C[m,n] = (t < lengths[m]) ? v : 0
// 64x64 tile, BK=16, 256 threads, 4x4 per thread.
__global__ __launch_bounds__(256) void gemm_nt(
    const float* __restrict__ A, int lda,
    const float* __restrict__ W, int ldw,
    const float* __restrict__ bias,
    const float* __restrict__ addv, int ldadd,
    float* __restrict__ C, int ldc,
    int M, int N, int K,
    const int* __restrict__ lengths, int t) {
  __shared__ __align__(16) float As[16][68];
  __shared__ __align__(16) float Ws[16][68];
  const int bm = blockIdx.y * 64;
  const int bn = blockIdx.x * 64;
  const int tid = threadIdx.x;
  const int ty = tid >> 4, tx = tid & 15;
  const int ar = tid >> 2;           // 0..63 (row within tile for loads)
  const int ak = (tid & 3) << 2;     // 0,4,8,12 (k within BK)
  const bool aok = (bm + ar) < M;
  const bool wok = (bn + ar) < N;
  const float* Aptr = A + (size_t)(bm + ar) * lda + ak;
  const float* Wptr = W + (size_t)(bn + ar) * ldw + ak;
  float acc[4][4] = {};
  for (int k0 = 0; k0 < K; k0 += 16) {
    float4 av = aok ? *reinterpret_cast<const float4*>(Aptr + k0)
                    : make_float4(0.f, 0.f, 0.f, 0.f);
    float4 wv = wok ? *reinterpret_cast<const float4*>(Wptr + k0)
                    : make_float4(0.f, 0.f, 0.f, 0.f);
    __syncthreads();
    As[ak + 0][ar] = av.x; As[ak + 1][ar] = av.y;
    As[ak + 2][ar] = av.z; As[ak + 3][ar] = av.w;
    Ws[ak + 0][ar] = wv.x; Ws[ak + 1][ar] = wv.y;
    Ws[ak + 2][ar] = wv.z; Ws[ak + 3][ar] = wv.w;
    __syncthreads();
#pragma unroll
    for (int kk = 0; kk < 16; ++kk) {
      float a[4], b[4];
      *reinterpret_cast<float4*>(a) =
          *reinterpret_cast<const float4*>(&As[kk][ty << 2]);
      *reinterpret_cast<float4*>(b) =
          *reinterpret_cast<const float4*>(&Ws[kk][tx << 2]);
#pragma unroll
      for (int i = 0; i < 4; ++i)
#pragma unroll
        for (int j = 0; j < 4; ++j) acc[i][j] += a[i] * b[j];
    }
  }
#pragma unroll
  for (int i = 0; i < 4; ++i) {
    const int m = bm + (ty << 2) + i;
    if (m >= M) continue;
    bool mask = true;
    if (lengths) mask = (t < lengths[m]);
#pragma unroll
    for (int j = 0; j < 4; ++j) {
      const int n = bn + (tx << 2) + j;
      if (n < N) {
        float v = acc[i][j];
        if (bias) v += bias[n];
        if (addv) v += addv[(size_t)m * ldadd + n];
        if (lengths && !mask) v = 0.f;
        C[(size_t)m * ldc + n] = v;
      }
    }
  }
}

// ---------------------------------------------------------------------------
// L2-normalize rows of fv (nrows x 512), in place. 4 waves/block, 1 row/wave.
__global__ __launch_bounds__(256) void norm_rows_k(float* __restrict__ fv, int nrows) {
  const int row = blockIdx.x * 4 + (threadIdx.x >> 6);
  const int lane = threadIdx.x & 63;
  if (row >= nrows) return;
  float* p = fv + (size_t)row * 512;
  float ss = 0.f;
  for (int d = lane; d < 512; d += 64) { float v = p[d]; ss += v * v; }
  for (int off = 32; off; off >>= 1) ss += __shfl_down(ss, off);
  ss = __shfl(ss, 0);
  const float inv = 1.f / fmaxf(sqrtf(ss), 1e-12f);
  for (int d = lane; d < 512; d += 64) p[d] *= inv;
}

// ---------------------------------------------------------------------------
// we[b,t,:] = embed_W[captions[b,t],:]  written to inputs[(b*20+t)*1024 + 512 ...]
__global__ __launch_bounds__(256) void gather_embed_k(
    const int* __restrict__ captions, const float* __restrict__ embed_W,
    float* __restrict__ inputs) {
  const int idx = blockIdx.x * 256 + threadIdx.x;
  if (idx >= Bb * Tt * 128) return;
  const int row = idx >> 7, e4 = idx & 127;
  const int tok = captions[row];
  const float4 v =
      *reinterpret_cast<const float4*>(embed_W + (size_t)tok * 512 + e4 * 4);
  *reinterpret_cast<float4*>(inputs + (size_t)row * 1024 + 512 + e4 * 4) = v;
}

// ---------------------------------------------------------------------------
// Fused attention per (b,t): scores over l=0..48, softmax, ctx -> inputs[b,t+1,:512]
__global__ __launch_bounds__(256) void attention_k(
    const float* __restrict__ att_fea, const float* __restrict__ att_h,
    const float* __restrict__ att_bias, const float* __restrict__ att_w,
    const float* __restrict__ fv, float* __restrict__ inputs) {
  const int b = blockIdx.x / 19, t = blockIdx.x % 19;
  __shared__ float hh[512];
  __shared__ float wv[512];
  __shared__ float sl[64];
  const int tid = threadIdx.x;
  const float* hp = att_h + (size_t)(b * 20 + t) * 512;
  for (int d = tid; d < 512; d += 256) { hh[d] = hp[d]; wv[d] = att_w[d]; }
  __syncthreads();
  const int wid = tid >> 6, lane = tid & 63;
  for (int l = wid; l < Ll; l += 4) {
    const float* fp = att_fea + (size_t)(b * Ll + l) * 512;
    const float bl = att_bias[l];
    float acc = 0.f;
    for (int d = lane; d < 512; d += 64) {
      float v = fp[d] + hh[d] + bl;
      acc += fmaxf(v, 0.f) * wv[d];
    }
    for (int off = 32; off; off >>= 1) acc += __shfl_down(acc, off);
    if (lane == 0) sl[l] = acc;
  }
  __syncthreads();
  if (wid == 0) {
    float v = (lane < Ll) ? sl[lane] : -INFINITY;
    float mx = v;
    for (int off = 32; off; off >>= 1) mx = fmaxf(mx, __shfl_xor(mx, off));
    float e = (lane < Ll) ? expf(v - mx) : 0.f;
    float s = e;
    for (int off = 32; off; off >>= 1) s += __shfl_xor(s, off);
    if (lane < Ll) sl[lane] = e / s;
  }
  __syncthreads();
  float* outp = inputs + (size_t)(b * 20 + t + 1) * 1024;
  for (int d = tid; d < 512; d += 256) {
    float acc = 0.f;
#pragma unroll 7
    for (int l = 0; l < Ll; ++l)
      acc += sl[l] * fv[(size_t)(b * Ll + l) * 512 + d];
    outp[d] = acc;
  }
}

// ---------------------------------------------------------------------------
// LSTM cell elementwise: g (64,2048) -> update h,c (64,512) where t < lengths[b]
__global__ __launch_bounds__(256) void lstm_cell_k(
    const float* __restrict__ g, float* __restrict__ h, float* __restrict__ c,
    const int* __restrict__ lengths, int t) {
  const int idx = blockIdx.x * 256 + threadIdx.x;
  if (idx >= Bb * Hh) return;
  const int b = idx >> 9, j = idx & 511;
  const float* gb = g + (size_t)b * 2048;
  const float gi = gb[j], gf = gb[512 + j], gg = gb[1024 + j], go = gb[1536 + j];
  const float si = 1.f / (1.f + expf(-gi));
  const float sf = 1.f / (1.f + expf(-gf));
  const float so = 1.f / (1.f + expf(-go));
  const float cn = sf * c[idx] + si * tanhf(gg);
  const float hn = so * tanhf(cn);
  if (t < lengths[b]) { h[idx] = hn; c[idx] = cn; }
}

// ---------------------------------------------------------------------------
extern "C" void kernel_launch(void* const* d_in, const int* in_sizes, int n_in,
                              void* d_out, int out_size, void* d_ws, size_t ws_size,
                              hipStream_t stream) {
  const float* feature_0 = (const float*)d_in[0];
  const float* features  = (const float*)d_in[1];
  // d_in[2] eng_embedding: unused by the reference
  const int*   captions  = (const int*)d_in[3];
  const int*   lengths   = (const int*)d_in[4];
  const float* embed_W   = (const float*)d_in[5];
  const float* W_ih      = (const float*)d_in[6];
  const float* W_hh      = (const float*)d_in[7];
  const float* b_ih      = (const float*)d_in[8];
  const float* b_hh      = (const float*)d_in[9];
  const float* fc_out_W  = (const float*)d_in[10];
  const float* fc_out_b  = (const float*)d_in[11];
  const float* att_vw_W  = (const float*)d_in[12];
  const float* att_hw_W  = (const float*)d_in[13];
  const float* att_bias  = (const float*)d_in[14];
  const float* att_w_W   = (const float*)d_in[15];
  const float* att_fc_v_W = (const float*)d_in[16];
  const float* att_fc_v_b = (const float*)d_in[17];
  const float* img_embed_W = (const float*)d_in[18];
  const float* img_embed_b = (const float*)d_in[19];
  float* out = (float*)d_out;

  // workspace layout
  char* ws = (char*)d_ws;
  size_t off = 0;
  auto alloc = [&](size_t bytes) {
    void* p = ws + off;
    off = (off + bytes + 255) & ~(size_t)255;
    return p;
  };
  float* f2      = (float*)alloc((size_t)Bb * Ll * 512 * 4);   // (B,49,512)
  float* fv      = (float*)alloc((size_t)Bb * Ll * 512 * 4);   // (B,49,512)
  float* att_fea = (float*)alloc((size_t)Bb * Ll * 512 * 4);   // (B,49,512)
  float* att_h   = (float*)alloc((size_t)Bb * Tt * 512 * 4);   // (B,20,512)
  float* inputs  = (float*)alloc((size_t)Bb * Tt * 1024 * 4);  // (B,20,1024)
  float* xg      = (float*)alloc((size_t)Bb * Tt * 2048 * 4);  // (B,20,2048)
  float* g       = (float*)alloc((size_t)Bb * 2048 * 4);       // (B,2048)
  float* h       = (float*)alloc((size_t)Bb * 512 * 4);
  float* c       = (float*)alloc((size_t)Bb * 512 * 4);
  (void)ws_size; (void)n_in; (void)in_sizes; (void)out_size;

  // 1. transpose features -> f2
  transpose_features_k<<<Bb * 2, 256, 0, stream>>>(features, f2);
  // 2. embedding gather -> inputs[:, :, 512:]
  gather_embed_k<<<(Bb * Tt * 128 + 255) / 256, 256, 0, stream>>>(captions, embed_W, inputs);
  // 3. fv = f2 @ att_fc_v_W^T + b  (3136,512,K=512)
  gemm_nt<<<dim3(8, 49), 256, 0, stream>>>(f2, 512, att_fc_v_W, 512, att_fc_v_b,
                                           nullptr, 0, fv, 512, Bb * Ll, 512, 512,
                                           nullptr, 0);
  // 4. L2-normalize fv rows
  norm_rows_k<<<(Bb * Ll + 3) / 4, 256, 0, stream>>>(fv, Bb * Ll);
  // 5. feas0 = feature_0 @ img_embed_W^T + b -> inputs[b,0,:512]  (ldc trick)
  gemm_nt<<<dim3(8, 1), 256, 0, stream>>>(feature_0, 2048, img_embed_W, 2048,
                                          img_embed_b, nullptr, 0, inputs,
                                          Tt * 1024, Bb, 512, 2048, nullptr, 0);
  // 6. att_fea = fv @ att_vw_W^T  (3136,512,512)
  gemm_nt<<<dim3(8, 49), 256, 0, stream>>>(fv, 512, att_vw_W, 512, nullptr,
                                           nullptr, 0, att_fea, 512, Bb * Ll, 512,
                                           512, nullptr, 0);
  // 7. att_h = we @ att_hw_W^T for all 1280 (b,t) rows (A = inputs[:,:,512:])
  gemm_nt<<<dim3(8, 20), 256, 0, stream>>>(inputs + 512, 1024, att_hw_W, 512,
                                           nullptr, nullptr, 0, att_h, 512,
                                           Bb * Tt, 512, 512, nullptr, 0);
  // 8. fused attention -> ctx into inputs[b,t+1,:512]
  attention_k<<<Bb * 19, 256, 0, stream>>>(att_fea, att_h, att_bias, att_w_W, fv,
                                           inputs);
  // 9. xg = inputs @ W_ih^T + b_ih  (1280,2048,K=1024)
  gemm_nt<<<dim3(32, 20), 256, 0, stream>>>(inputs, 1024, W_ih, 1024, b_ih,
                                            nullptr, 0, xg, 2048, Bb * Tt, 2048,
                                            1024, nullptr, 0);
  // 10. LSTM loop
  hipMemsetAsync(h, 0, (size_t)Bb * 512 * 4, stream);
  hipMemsetAsync(c, 0, (size_t)Bb * 512 * 4, stream);
  for (int t = 0; t < Tt; ++t) {
    // gates g = h @ W_hh^T + b_hh + xg[:,t,:]
    gemm_nt<<<dim3(32, 1), 256, 0, stream>>>(h, 512, W_hh, 512, b_hh,
                                             xg + (size_t)t * 2048, Tt * 2048, g,
                                             2048, Bb, 2048, 512, nullptr, 0);
    lstm_cell_k<<<(Bb * Hh + 255) / 256, 256, 0, stream>>>(g, h, c, lengths, t);
    // logits = h @ fc_out_W^T + fc_out_b, masked -> out[:, t, :]
    gemm_nt<<<dim3((Vv + 63) / 64, 1), 256, 0, stream>>>(
        h, 512, fc_out_W, 512, fc_out_b, nullptr, 0, out + (size_t)t * Vv,
        Tt * Vv, Bb, Vv, 512, lengths, t);
  }
}

// Round 6
// 1035.801 us; speedup vs baseline: 1.9743x; 1.9743x over previous
//
#include <hip/hip_runtime.h>
#include <math.h>

#define Bb 64
#define Tt 20
#define Vv 20000
#define Ee 512
#define Hh 512
#define Ll 49

typedef __attribute__((ext_vector_type(8))) short bf16x8;
typedef __attribute__((ext_vector_type(4))) float f32x4;

__device__ inline ushort f2bf(float x) {
  uint u = __builtin_bit_cast(uint, x);
  u += 0x7fffu + ((u >> 16) & 1u);
  return (ushort)(u >> 16);
}

// ---------------------------------------------------------------------------
// Batched fp32 -> bf16 convert (8 segments), 8 elems per thread-iter.
struct Cvt8 {
  const float* s[8];
  ushort* d[8];
  int cum8[9];  // cumulative sizes in 8-element units
};

__global__ __launch_bounds__(256) void cvt_k(Cvt8 p, int total8) {
  for (int i = blockIdx.x * 256 + threadIdx.x; i < total8;
       i += gridDim.x * 256) {
    int seg = 0;
    while (i >= p.cum8[seg + 1]) ++seg;
    const int j = i - p.cum8[seg];
    const float4* sp = (const float4*)p.s[seg];
    const float4 a = sp[j * 2];
    const float4 b = sp[j * 2 + 1];
    ushort r[8] = {f2bf(a.x), f2bf(a.y), f2bf(a.z), f2bf(a.w),
                   f2bf(b.x), f2bf(b.y), f2bf(b.z), f2bf(b.w)};
    ((uint4*)p.d[seg])[j] = *(uint4*)r;
  }
}

// ---------------------------------------------------------------------------
// features (B,512,1,7,7) -> f2_bf16 (B,49,512)
__global__ __launch_bounds__(256) void transpose_features_k(
    const float* __restrict__ feat, ushort* __restrict__ f2) {
  __shared__ float lds[256 * 49];
  const int b = blockIdx.x >> 1, half = blockIdx.x & 1;
  const int c0 = half * 256;
  const float* src = feat + ((size_t)b * 512 + c0) * 49;
  for (int i = threadIdx.x; i < 256 * 49; i += 256) lds[i] = src[i];
  __syncthreads();
  for (int l = 0; l < 49; ++l)
    f2[((size_t)b * 49 + l) * 512 + c0 + threadIdx.x] =
        f2bf(lds[threadIdx.x * 49 + l]);
}

// ---------------------------------------------------------------------------
// Generic MFMA NT GEMM, bf16 in / fp32 accum, no LDS, no barriers.
// C[m,n] = sum_k A[m*lda+k]*W[n*ldw+k] (+bias[n]) (+addv[m*ldadd+n]);
// lengths!=null: zero rows with t >= lengths[m]. Cf fp32 and/or Cb bf16 out.
template <int Kc, int MT>
__global__ __launch_bounds__(256) void gemm_mfma(
    const ushort* __restrict__ A, int lda, const ushort* __restrict__ W,
    int ldw, const float* __restrict__ bias, const float* __restrict__ addv,
    int ldadd, float* __restrict__ Cf, ushort* __restrict__ Cb, int ldc, int N,
    const int* __restrict__ lengths, int t) {
  const int wid = threadIdx.x >> 6, lane = threadIdx.x & 63;
  const int ntile = blockIdx.x * 4 + wid;
  if (ntile * 16 >= N) return;
  const int m0 = blockIdx.y * (MT * 16);
  const int ar = lane & 15;          // A-row / B-col within tile
  const int koff = (lane >> 4) * 8;  // this lane's 8-elem k-group
  const ushort* Ap = A + (size_t)(m0 + ar) * lda + koff;
  const ushort* Wp = W + (size_t)(ntile * 16 + ar) * ldw + koff;
  f32x4 acc[MT];
#pragma unroll
  for (int i = 0; i < MT; ++i) acc[i] = (f32x4)(0.f);
#pragma unroll 16
  for (int k0 = 0; k0 < Kc; k0 += 32) {
    const bf16x8 b = *(const bf16x8*)(Wp + k0);
#pragma unroll
    for (int mt = 0; mt < MT; ++mt) {
      const bf16x8 a = *(const bf16x8*)(Ap + (size_t)mt * 16 * lda + k0);
      acc[mt] = __builtin_amdgcn_mfma_f32_16x16x32_bf16(a, b, acc[mt], 0, 0, 0);
    }
  }
  const int col = ntile * 16 + ar;
  const float bv = bias ? bias[col] : 0.f;
#pragma unroll
  for (int mt = 0; mt < MT; ++mt) {
    const int rbase = m0 + mt * 16 + (lane >> 4) * 4;
#pragma unroll
    for (int j = 0; j < 4; ++j) {
      const int row = rbase + j;
      float v = acc[mt][j] + bv;
      if (addv) v += addv[(size_t)row * ldadd + col];
      if (lengths && t >= lengths[row]) v = 0.f;
      if (Cf) Cf[(size_t)row * ldc + col] = v;
      if (Cb) Cb[(size_t)row * ldc + col] = f2bf(v);
    }
  }
}

// ---------------------------------------------------------------------------
// L2-normalize rows of fv (nrows x 512) in place; also emit bf16 copy.
__global__ __launch_bounds__(256) void norm_rows_k(float* __restrict__ fv,
                                                   ushort* __restrict__ fvb,
                                                   int nrows) {
  const int row = blockIdx.x * 4 + (threadIdx.x >> 6);
  const int lane = threadIdx.x & 63;
  if (row >= nrows) return;
  float* p = fv + (size_t)row * 512;
  ushort* pb = fvb + (size_t)row * 512;
  float ss = 0.f;
  for (int d = lane; d < 512; d += 64) { float v = p[d]; ss += v * v; }
  for (int off = 32; off; off >>= 1) ss += __shfl_down(ss, off);
  ss = __shfl(ss, 0);
  const float inv = 1.f / fmaxf(sqrtf(ss), 1e-12f);
  for (int d = lane; d < 512; d += 64) {
    const float v = p[d] * inv;
    p[d] = v;
    pb[d] = f2bf(v);
  }
}

// ---------------------------------------------------------------------------
// we[b,t,:] = bf16(embed_W[captions[b,t],:]) -> inputs[(b*20+t)*1024+512..]
__global__ __launch_bounds__(256) void gather_embed_k(
    const int* __restrict__ captions, const float* __restrict__ embed_W,
    ushort* __restrict__ inputs) {
  const int idx = blockIdx.x * 256 + threadIdx.x;
  if (idx >= Bb * Tt * 64) return;
  const int row = idx >> 6, e8 = idx & 63;
  const int tok = captions[row];
  const float4* sp = (const float4*)(embed_W + (size_t)tok * 512 + e8 * 8);
  const float4 a = sp[0], b = sp[1];
  ushort r[8] = {f2bf(a.x), f2bf(a.y), f2bf(a.z), f2bf(a.w),
                 f2bf(b.x), f2bf(b.y), f2bf(b.z), f2bf(b.w)};
  *(uint4*)(inputs + (size_t)row * 1024 + 512 + e8 * 8) = *(uint4*)r;
}

// ---------------------------------------------------------------------------
// Fused attention per (b,t): scores, softmax, ctx -> inputs[b,t+1,:512] bf16
__global__ __launch_bounds__(256) void attention_k(
    const float* __restrict__ att_fea, const float* __restrict__ att_h,
    const float* __restrict__ att_bias, const float* __restrict__ att_w,
    const float* __restrict__ fv, ushort* __restrict__ inputs) {
  const int b = blockIdx.x / 19, t = blockIdx.x % 19;
  __shared__ float hh[512];
  __shared__ float wv[512];
  __shared__ float sl[64];
  const int tid = threadIdx.x;
  const float* hp = att_h + (size_t)(b * 20 + t) * 512;
  for (int d = tid; d < 512; d += 256) { hh[d] = hp[d]; wv[d] = att_w[d]; }
  __syncthreads();
  const int wid = tid >> 6, lane = tid & 63;
  for (int l = wid; l < Ll; l += 4) {
    const float* fp = att_fea + (size_t)(b * Ll + l) * 512;
    const float bl = att_bias[l];
    float acc = 0.f;
    for (int d = lane; d < 512; d += 64) {
      float v = fp[d] + hh[d] + bl;
      acc += fmaxf(v, 0.f) * wv[d];
    }
    for (int off = 32; off; off >>= 1) acc += __shfl_down(acc, off);
    if (lane == 0) sl[l] = acc;
  }
  __syncthreads();
  if (wid == 0) {
    float v = (lane < Ll) ? sl[lane] : -INFINITY;
    float mx = v;
    for (int off = 32; off; off >>= 1) mx = fmaxf(mx, __shfl_xor(mx, off));
    float e = (lane < Ll) ? expf(v - mx) : 0.f;
    float s = e;
    for (int off = 32; off; off >>= 1) s += __shfl_xor(s, off);
    if (lane < Ll) sl[lane] = e / s;
  }
  __syncthreads();
  ushort* outp = inputs + (size_t)(b * 20 + t + 1) * 1024;
  for (int d = tid; d < 512; d += 256) {
    float acc = 0.f;
#pragma unroll 7
    for (int l = 0; l < Ll; ++l)
      acc += sl[l] * fv[(size_t)(b * Ll + l) * 512 + d];
    outp[d] = f2bf(acc);
  }
}

// ---------------------------------------------------------------------------
// LSTM cell elementwise: g (64,2048) -> c fp32, h bf16, masked by lengths.
__global__ __launch_bounds__(256) void lstm_cell_k(
    const float* __restrict__ g, ushort* __restrict__ hb, float* __restrict__ c,
    const int* __restrict__ lengths, int t) {
  const int idx = blockIdx.x * 256 + threadIdx.x;
  if (idx >= Bb * Hh) return;
  const int b = idx >> 9, j = idx & 511;
  const float* gb = g + (size_t)b * 2048;
  const float gi = gb[j], gf = gb[512 + j], gg = gb[1024 + j],
              go = gb[1536 + j];
  const float si = 1.f / (1.f + expf(-gi));
  const float sf = 1.f / (1.f + expf(-gf));
  const float so = 1.f / (1.f + expf(-go));
  const float cn = sf * c[idx] + si * tanhf(gg);
  const float hn = so * tanhf(cn);
  if (t < lengths[b]) {
    c[idx] = cn;
    hb[idx] = f2bf(hn);
  }
}

// ---------------------------------------------------------------------------
extern "C" void kernel_launch(void* const* d_in, const int* in_sizes, int n_in,
                              void* d_out, int out_size, void* d_ws,
                              size_t ws_size, hipStream_t stream) {
  const float* feature_0 = (const float*)d_in[0];
  const float* features = (const float*)d_in[1];
  const int* captions = (const int*)d_in[3];
  const int* lengths = (const int*)d_in[4];
  const float* embed_W = (const float*)d_in[5];
  const float* W_ih = (const float*)d_in[6];
  const float* W_hh = (const float*)d_in[7];
  const float* b_ih = (const float*)d_in[8];
  const float* b_hh = (const float*)d_in[9];
  const float* fc_out_W = (const float*)d_in[10];
  const float* fc_out_b = (const float*)d_in[11];
  const float* att_vw_W = (const float*)d_in[12];
  const float* att_hw_W = (const float*)d_in[13];
  const float* att_bias = (const float*)d_in[14];
  const float* att_w_W = (const float*)d_in[15];
  const float* att_fc_v_W = (const float*)d_in[16];
  const float* att_fc_v_b = (const float*)d_in[17];
  const float* img_embed_W = (const float*)d_in[18];
  const float* img_embed_b = (const float*)d_in[19];
  float* out = (float*)d_out;

  char* ws = (char*)d_ws;
  size_t off = 0;
  auto alloc = [&](size_t bytes) {
    void* p = ws + off;
    off = (off + bytes + 255) & ~(size_t)255;
    return p;
  };
  // bf16 weight copies
  ushort* att_fc_v_Wb = (ushort*)alloc((size_t)512 * 512 * 2);
  ushort* att_vw_Wb   = (ushort*)alloc((size_t)512 * 512 * 2);
  ushort* att_hw_Wb   = (ushort*)alloc((size_t)512 * 512 * 2);
  ushort* W_ihb       = (ushort*)alloc((size_t)2048 * 1024 * 2);
  ushort* W_hhb       = (ushort*)alloc((size_t)2048 * 512 * 2);
  ushort* fc_out_Wb   = (ushort*)alloc((size_t)Vv * 512 * 2);
  ushort* img_embedb  = (ushort*)alloc((size_t)512 * 2048 * 2);
  ushort* feature_0b  = (ushort*)alloc((size_t)Bb * 2048 * 2);
  // activations
  ushort* f2      = (ushort*)alloc((size_t)Bb * Ll * 512 * 2);
  float*  fv      = (float*)alloc((size_t)Bb * Ll * 512 * 4);
  ushort* fvb     = (ushort*)alloc((size_t)Bb * Ll * 512 * 2);
  float*  att_fea = (float*)alloc((size_t)Bb * Ll * 512 * 4);
  float*  att_h   = (float*)alloc((size_t)Bb * Tt * 512 * 4);
  ushort* inputs  = (ushort*)alloc((size_t)Bb * Tt * 1024 * 2);
  float*  xg      = (float*)alloc((size_t)Bb * Tt * 2048 * 4);
  float*  g       = (float*)alloc((size_t)Bb * 2048 * 4);
  ushort* hb      = (ushort*)alloc((size_t)Bb * 512 * 2);
  float*  c       = (float*)alloc((size_t)Bb * 512 * 4);
  (void)ws_size; (void)n_in; (void)in_sizes; (void)out_size;

  // 0. convert weights + feature_0 to bf16 (one fused kernel)
  Cvt8 cv;
  const float* srcs[8] = {att_fc_v_W, att_vw_W, att_hw_W, W_ih,
                          W_hh,       fc_out_W, img_embed_W, feature_0};
  ushort* dsts[8] = {att_fc_v_Wb, att_vw_Wb, att_hw_Wb, W_ihb,
                     W_hhb,       fc_out_Wb, img_embedb, feature_0b};
  const int sz8[8] = {512 * 512 / 8,   512 * 512 / 8, 512 * 512 / 8,
                      2048 * 1024 / 8, 2048 * 512 / 8, Vv * 512 / 8,
                      512 * 2048 / 8,  Bb * 2048 / 8};
  int cum = 0;
  for (int i = 0; i < 8; ++i) {
    cv.s[i] = srcs[i];
    cv.d[i] = dsts[i];
    cv.cum8[i] = cum;
    cum += sz8[i];
  }
  cv.cum8[8] = cum;
  cvt_k<<<2048, 256, 0, stream>>>(cv, cum);

  // 1. transpose features -> f2 (bf16)
  transpose_features_k<<<Bb * 2, 256, 0, stream>>>(features, f2);
  // 2. embedding gather -> inputs[:,:,512:] (bf16)
  gather_embed_k<<<(Bb * Tt * 64 + 255) / 256, 256, 0, stream>>>(
      captions, embed_W, inputs);
  // 3. fv = f2 @ att_fc_v_W^T + b   (3136,512,K=512) -> fp32
  gemm_mfma<512, 4><<<dim3(8, 49), 256, 0, stream>>>(
      f2, 512, att_fc_v_Wb, 512, att_fc_v_b, nullptr, 0, fv, nullptr, 512, 512,
      nullptr, 0);
  // 4. L2-normalize fv rows (fp32 + bf16 copy)
  norm_rows_k<<<(Bb * Ll + 3) / 4, 256, 0, stream>>>(fv, fvb, Bb * Ll);
  // 5. feas0 = feature_0 @ img_embed_W^T + b -> inputs[b,0,:512] (bf16)
  gemm_mfma<2048, 4><<<dim3(8, 1), 256, 0, stream>>>(
      feature_0b, 2048, img_embedb, 2048, img_embed_b, nullptr, 0, nullptr,
      inputs, Tt * 1024, 512, nullptr, 0);
  // 6. att_fea = fv @ att_vw_W^T  (3136,512,512) -> fp32
  gemm_mfma<512, 4><<<dim3(8, 49), 256, 0, stream>>>(
      fvb, 512, att_vw_Wb, 512, nullptr, nullptr, 0, att_fea, nullptr, 512,
      512, nullptr, 0);
  // 7. att_h = we @ att_hw_W^T  (1280,512,K=512) -> fp32
  gemm_mfma<512, 4><<<dim3(8, 20), 256, 0, stream>>>(
      inputs + 512, 1024, att_hw_Wb, 512, nullptr, nullptr, 0, att_h, nullptr,
      512, 512, nullptr, 0);
  // 8. fused attention -> ctx into inputs[b,t+1,:512] (bf16)
  attention_k<<<Bb * 19, 256, 0, stream>>>(att_fea, att_h, att_bias, att_w_W,
                                           fv, inputs);
  // 9. xg = inputs @ W_ih^T + b_ih  (1280,2048,K=1024) -> fp32
  gemm_mfma<1024, 4><<<dim3(32, 20), 256, 0, stream>>>(
      inputs, 1024, W_ihb, 1024, b_ih, nullptr, 0, xg, nullptr, 2048, 2048,
      nullptr, 0);
  // 10. LSTM loop
  hipMemsetAsync(hb, 0, (size_t)Bb * 512 * 2, stream);
  hipMemsetAsync(c, 0, (size_t)Bb * 512 * 4, stream);
  for (int t = 0; t < Tt; ++t) {
    // gates g = h @ W_hh^T + b_hh + xg[:,t,:]   (64,2048,K=512)
    gemm_mfma<512, 1><<<dim3(32, 4), 256, 0, stream>>>(
        hb, 512, W_hhb, 512, b_hh, xg + (size_t)t * 2048, Tt * 2048, g,
        nullptr, 2048, 2048, nullptr, 0);
    lstm_cell_k<<<(Bb * Hh + 255) / 256, 256, 0, stream>>>(g, hb, c, lengths,
                                                           t);
    // logits = h @ fc_out_W^T + b, masked -> out[:,t,:]  (64,20000,K=512)
    gemm_mfma<512, 4><<<dim3(313, 1), 256, 0, stream>>>(
        hb, 512, fc_out_Wb, 512, fc_out_b, nullptr, 0, out + (size_t)t * Vv,
        nullptr, Tt * Vv, Vv, lengths, t);
  }
}

// Round 7
// 894.087 us; speedup vs baseline: 2.2872x; 1.1585x over previous
//
#include <hip/hip_runtime.h>
#include <math.h>

#define Bb 64
#define Tt 20
#define Vv 20000
#define Ee 512
#define Hh 512
#define Ll 49

typedef __attribute__((ext_vector_type(8))) short bf16x8;
typedef __attribute__((ext_vector_type(4))) float f32x4;

__device__ inline ushort f2bf(float x) {
  uint u = __builtin_bit_cast(uint, x);
  u += 0x7fffu + ((u >> 16) & 1u);
  return (ushort)(u >> 16);
}

// ---------------------------------------------------------------------------
// Batched fp32 -> bf16 convert (8 segments), 8 elems per thread-iter.
struct Cvt8 {
  const float* s[8];
  ushort* d[8];
  int cum8[9];  // cumulative sizes in 8-element units
};

__global__ __launch_bounds__(256) void cvt_k(Cvt8 p, int total8) {
  for (int i = blockIdx.x * 256 + threadIdx.x; i < total8;
       i += gridDim.x * 256) {
    int seg = 0;
    while (i >= p.cum8[seg + 1]) ++seg;
    const int j = i - p.cum8[seg];
    const float4* sp = (const float4*)p.s[seg];
    const float4 a = sp[j * 2];
    const float4 b = sp[j * 2 + 1];
    ushort r[8] = {f2bf(a.x), f2bf(a.y), f2bf(a.z), f2bf(a.w),
                   f2bf(b.x), f2bf(b.y), f2bf(b.z), f2bf(b.w)};
    ((uint4*)p.d[seg])[j] = *(uint4*)r;
  }
}

// ---------------------------------------------------------------------------
// features (B,512,1,7,7) -> f2_bf16 (B,49,512)
__global__ __launch_bounds__(256) void transpose_features_k(
    const float* __restrict__ feat, ushort* __restrict__ f2) {
  __shared__ float lds[256 * 49];
  const int b = blockIdx.x >> 1, half = blockIdx.x & 1;
  const int c0 = half * 256;
  const float* src = feat + ((size_t)b * 512 + c0) * 49;
  for (int i = threadIdx.x; i < 256 * 49; i += 256) lds[i] = src[i];
  __syncthreads();
  for (int l = 0; l < 49; ++l)
    f2[((size_t)b * 49 + l) * 512 + c0 + threadIdx.x] =
        f2bf(lds[threadIdx.x * 49 + l]);
}

// ---------------------------------------------------------------------------
// Generic MFMA NT GEMM, bf16 in / fp32 accum, no LDS, no barriers.
// C[m,n] = sum_k A[m*lda+k]*W[n*ldw+k] (+bias[n]) (+addv[m*ldadd+n]);
// lengths!=null: row r maps to (b=r/20, t=r%20); zero rows with t>=lengths[b].
// Cf fp32 and/or Cb bf16 out. Wave computes MT 16-row m-tiles x one 16-col
// n-tile.
template <int Kc, int MT>
__global__ __launch_bounds__(256) void gemm_mfma(
    const ushort* __restrict__ A, int lda, const ushort* __restrict__ W,
    int ldw, const float* __restrict__ bias, const float* __restrict__ addv,
    int ldadd, float* __restrict__ Cf, ushort* __restrict__ Cb, int ldc, int N,
    const int* __restrict__ lengths) {
  const int wid = threadIdx.x >> 6, lane = threadIdx.x & 63;
  const int ntile = blockIdx.x * 4 + wid;
  if (ntile * 16 >= N) return;
  const int m0 = blockIdx.y * (MT * 16);
  const int ar = lane & 15;          // A-row / B-col within tile
  const int koff = (lane >> 4) * 8;  // this lane's 8-elem k-group
  const ushort* Ap = A + (size_t)(m0 + ar) * lda + koff;
  const ushort* Wp = W + (size_t)(ntile * 16 + ar) * ldw + koff;
  f32x4 acc[MT];
#pragma unroll
  for (int i = 0; i < MT; ++i) acc[i] = (f32x4)(0.f);
  for (int k0 = 0; k0 < Kc; k0 += 128) {
#pragma unroll
    for (int kk = 0; kk < 4; ++kk) {
      const int k = k0 + kk * 32;
      const bf16x8 b = *(const bf16x8*)(Wp + k);
#pragma unroll
      for (int mt = 0; mt < MT; ++mt) {
        const bf16x8 a = *(const bf16x8*)(Ap + (size_t)mt * 16 * lda + k);
        acc[mt] =
            __builtin_amdgcn_mfma_f32_16x16x32_bf16(a, b, acc[mt], 0, 0, 0);
      }
    }
  }
  const int col = ntile * 16 + ar;
  const float bv = bias ? bias[col] : 0.f;
#pragma unroll
  for (int mt = 0; mt < MT; ++mt) {
    const int rbase = m0 + mt * 16 + (lane >> 4) * 4;
#pragma unroll
    for (int j = 0; j < 4; ++j) {
      const int row = rbase + j;
      float v = acc[mt][j] + bv;
      if (addv) v += addv[(size_t)row * ldadd + col];
      if (lengths) {
        const int bidx = row / Tt, tidx = row - bidx * Tt;
        if (tidx >= lengths[bidx]) v = 0.f;
      }
      if (Cf) Cf[(size_t)row * ldc + col] = v;
      if (Cb) Cb[(size_t)row * ldc + col] = f2bf(v);
    }
  }
}

// ---------------------------------------------------------------------------
// L2-normalize rows of fv (nrows x 512) in place; also emit bf16 copy.
__global__ __launch_bounds__(256) void norm_rows_k(float* __restrict__ fv,
                                                   ushort* __restrict__ fvb,
                                                   int nrows) {
  const int row = blockIdx.x * 4 + (threadIdx.x >> 6);
  const int lane = threadIdx.x & 63;
  if (row >= nrows) return;
  float* p = fv + (size_t)row * 512;
  ushort* pb = fvb + (size_t)row * 512;
  float ss = 0.f;
  for (int d = lane; d < 512; d += 64) { float v = p[d]; ss += v * v; }
  for (int off = 32; off; off >>= 1) ss += __shfl_down(ss, off);
  ss = __shfl(ss, 0);
  const float inv = 1.f / fmaxf(sqrtf(ss), 1e-12f);
  for (int d = lane; d < 512; d += 64) {
    const float v = p[d] * inv;
    p[d] = v;
    pb[d] = f2bf(v);
  }
}

// ---------------------------------------------------------------------------
// we[b,t,:] = bf16(embed_W[captions[b,t],:]) -> inputs[(b*20+t)*1024+512..]
__global__ __launch_bounds__(256) void gather_embed_k(
    const int* __restrict__ captions, const float* __restrict__ embed_W,
    ushort* __restrict__ inputs) {
  const int idx = blockIdx.x * 256 + threadIdx.x;
  if (idx >= Bb * Tt * 64) return;
  const int row = idx >> 6, e8 = idx & 63;
  const int tok = captions[row];
  const float4* sp = (const float4*)(embed_W + (size_t)tok * 512 + e8 * 8);
  const float4 a = sp[0], b = sp[1];
  ushort r[8] = {f2bf(a.x), f2bf(a.y), f2bf(a.z), f2bf(a.w),
                 f2bf(b.x), f2bf(b.y), f2bf(b.z), f2bf(b.w)};
  *(uint4*)(inputs + (size_t)row * 1024 + 512 + e8 * 8) = *(uint4*)r;
}

// ---------------------------------------------------------------------------
// Fused attention per (b,t): scores, softmax, ctx -> inputs[b,t+1,:512] bf16
__global__ __launch_bounds__(256) void attention_k(
    const float* __restrict__ att_fea, const float* __restrict__ att_h,
    const float* __restrict__ att_bias, const float* __restrict__ att_w,
    const float* __restrict__ fv, ushort* __restrict__ inputs) {
  const int b = blockIdx.x / 19, t = blockIdx.x % 19;
  __shared__ float hh[512];
  __shared__ float wv[512];
  __shared__ float sl[64];
  const int tid = threadIdx.x;
  const float* hp = att_h + (size_t)(b * 20 + t) * 512;
  for (int d = tid; d < 512; d += 256) { hh[d] = hp[d]; wv[d] = att_w[d]; }
  __syncthreads();
  const int wid = tid >> 6, lane = tid & 63;
  for (int l = wid; l < Ll; l += 4) {
    const float* fp = att_fea + (size_t)(b * Ll + l) * 512;
    const float bl = att_bias[l];
    float acc = 0.f;
    for (int d = lane; d < 512; d += 64) {
      float v = fp[d] + hh[d] + bl;
      acc += fmaxf(v, 0.f) * wv[d];
    }
    for (int off = 32; off; off >>= 1) acc += __shfl_down(acc, off);
    if (lane == 0) sl[l] = acc;
  }
  __syncthreads();
  if (wid == 0) {
    float v = (lane < Ll) ? sl[lane] : -INFINITY;
    float mx = v;
    for (int off = 32; off; off >>= 1) mx = fmaxf(mx, __shfl_xor(mx, off));
    float e = (lane < Ll) ? expf(v - mx) : 0.f;
    float s = e;
    for (int off = 32; off; off >>= 1) s += __shfl_xor(s, off);
    if (lane < Ll) sl[lane] = e / s;
  }
  __syncthreads();
  ushort* outp = inputs + (size_t)(b * 20 + t + 1) * 1024;
  for (int d = tid; d < 512; d += 256) {
    float acc = 0.f;
#pragma unroll 7
    for (int l = 0; l < Ll; ++l)
      acc += sl[l] * fv[(size_t)(b * Ll + l) * 512 + d];
    outp[d] = f2bf(acc);
  }
}

// ---------------------------------------------------------------------------
// Fused LSTM step: gates GEMM (h@W_hh^T + b_hh + xg_t) + cell elementwise.
// Block bx owns h-cols [bx*16, bx*16+16); wave w computes gate w's tile via
// MFMA; LDS exchange; then cell update for those cols. h double-buffered
// (hcur read-only, hnext written) to avoid cross-block races. Also records
// hseq[b*20+t] for the batched logits GEMM.
__global__ __launch_bounds__(256) void lstm_step_k(
    const ushort* __restrict__ hcur, ushort* __restrict__ hnext,
    float* __restrict__ c, const ushort* __restrict__ Whh,
    const float* __restrict__ b_hh, const float* __restrict__ xg,
    const int* __restrict__ lengths, ushort* __restrict__ hseq, int t) {
  __shared__ float gl[4][64][16];
  const int wid = threadIdx.x >> 6, lane = threadIdx.x & 63;
  const int j0 = blockIdx.x * 16;
  const int ar = lane & 15;
  const int koff = (lane >> 4) * 8;
  const int n = wid * 512 + j0 + ar;  // gate column in 4H space
  const ushort* Wp = Whh + (size_t)n * 512 + koff;
  const ushort* Ap = hcur + (size_t)ar * 512 + koff;
  f32x4 acc[4];
#pragma unroll
  for (int i = 0; i < 4; ++i) acc[i] = (f32x4)(0.f);
  for (int k0 = 0; k0 < 512; k0 += 128) {
#pragma unroll
    for (int kk = 0; kk < 4; ++kk) {
      const int k = k0 + kk * 32;
      const bf16x8 b = *(const bf16x8*)(Wp + k);
#pragma unroll
      for (int mt = 0; mt < 4; ++mt) {
        const bf16x8 a = *(const bf16x8*)(Ap + (size_t)mt * 16 * 512 + k);
        acc[mt] =
            __builtin_amdgcn_mfma_f32_16x16x32_bf16(a, b, acc[mt], 0, 0, 0);
      }
    }
  }
  const float bh = b_hh[n];
#pragma unroll
  for (int mt = 0; mt < 4; ++mt) {
    const int rbase = mt * 16 + (lane >> 4) * 4;
#pragma unroll
    for (int j = 0; j < 4; ++j) {
      const int row = rbase + j;  // batch index
      gl[wid][row][ar] =
          acc[mt][j] + bh + xg[((size_t)row * Tt + t) * 2048 + n];
    }
  }
  __syncthreads();
  // cell phase: 64 rows x 16 cols, 4 elems per thread
#pragma unroll
  for (int k = 0; k < 4; ++k) {
    const int e = threadIdx.x + k * 256;
    const int row = e >> 4, col = e & 15;
    const float gi = gl[0][row][col];
    const float gf = gl[1][row][col];
    const float gg = gl[2][row][col];
    const float go = gl[3][row][col];
    const float si = 1.f / (1.f + expf(-gi));
    const float sf = 1.f / (1.f + expf(-gf));
    const float so = 1.f / (1.f + expf(-go));
    const int hidx = row * 512 + j0 + col;
    const float cn = sf * c[hidx] + si * tanhf(gg);
    const float hn = so * tanhf(cn);
    ushort hv;
    if (t < lengths[row]) {
      c[hidx] = cn;
      hv = f2bf(hn);
    } else {
      hv = hcur[hidx];
    }
    hnext[hidx] = hv;
    hseq[((size_t)row * Tt + t) * 512 + j0 + col] = hv;
  }
}

// ---------------------------------------------------------------------------
extern "C" void kernel_launch(void* const* d_in, const int* in_sizes, int n_in,
                              void* d_out, int out_size, void* d_ws,
                              size_t ws_size, hipStream_t stream) {
  const float* feature_0 = (const float*)d_in[0];
  const float* features = (const float*)d_in[1];
  const int* captions = (const int*)d_in[3];
  const int* lengths = (const int*)d_in[4];
  const float* embed_W = (const float*)d_in[5];
  const float* W_ih = (const float*)d_in[6];
  const float* W_hh = (const float*)d_in[7];
  const float* b_ih = (const float*)d_in[8];
  const float* b_hh = (const float*)d_in[9];
  const float* fc_out_W = (const float*)d_in[10];
  const float* fc_out_b = (const float*)d_in[11];
  const float* att_vw_W = (const float*)d_in[12];
  const float* att_hw_W = (const float*)d_in[13];
  const float* att_bias = (const float*)d_in[14];
  const float* att_w_W = (const float*)d_in[15];
  const float* att_fc_v_W = (const float*)d_in[16];
  const float* att_fc_v_b = (const float*)d_in[17];
  const float* img_embed_W = (const float*)d_in[18];
  const float* img_embed_b = (const float*)d_in[19];
  float* out = (float*)d_out;

  char* ws = (char*)d_ws;
  size_t off = 0;
  auto alloc = [&](size_t bytes) {
    void* p = ws + off;
    off = (off + bytes + 255) & ~(size_t)255;
    return p;
  };
  // bf16 weight copies
  ushort* att_fc_v_Wb = (ushort*)alloc((size_t)512 * 512 * 2);
  ushort* att_vw_Wb   = (ushort*)alloc((size_t)512 * 512 * 2);
  ushort* att_hw_Wb   = (ushort*)alloc((size_t)512 * 512 * 2);
  ushort* W_ihb       = (ushort*)alloc((size_t)2048 * 1024 * 2);
  ushort* W_hhb       = (ushort*)alloc((size_t)2048 * 512 * 2);
  ushort* fc_out_Wb   = (ushort*)alloc((size_t)Vv * 512 * 2);
  ushort* img_embedb  = (ushort*)alloc((size_t)512 * 2048 * 2);
  ushort* feature_0b  = (ushort*)alloc((size_t)Bb * 2048 * 2);
  // activations
  ushort* f2      = (ushort*)alloc((size_t)Bb * Ll * 512 * 2);
  float*  fv      = (float*)alloc((size_t)Bb * Ll * 512 * 4);
  ushort* fvb     = (ushort*)alloc((size_t)Bb * Ll * 512 * 2);
  float*  att_fea = (float*)alloc((size_t)Bb * Ll * 512 * 4);
  float*  att_h   = (float*)alloc((size_t)Bb * Tt * 512 * 4);
  ushort* inputs  = (ushort*)alloc((size_t)Bb * Tt * 1024 * 2);
  float*  xg      = (float*)alloc((size_t)Bb * Tt * 2048 * 4);
  ushort* hseq    = (ushort*)alloc((size_t)Bb * Tt * 512 * 2);
  ushort* h0      = (ushort*)alloc((size_t)Bb * 512 * 2);
  ushort* h1      = (ushort*)alloc((size_t)Bb * 512 * 2);
  float*  c       = (float*)alloc((size_t)Bb * 512 * 4);
  (void)ws_size; (void)n_in; (void)in_sizes; (void)out_size;

  // 0. convert weights + feature_0 to bf16 (one fused kernel)
  Cvt8 cv;
  const float* srcs[8] = {att_fc_v_W, att_vw_W, att_hw_W, W_ih,
                          W_hh,       fc_out_W, img_embed_W, feature_0};
  ushort* dsts[8] = {att_fc_v_Wb, att_vw_Wb, att_hw_Wb, W_ihb,
                     W_hhb,       fc_out_Wb, img_embedb, feature_0b};
  const int sz8[8] = {512 * 512 / 8,   512 * 512 / 8, 512 * 512 / 8,
                      2048 * 1024 / 8, 2048 * 512 / 8, Vv * 512 / 8,
                      512 * 2048 / 8,  Bb * 2048 / 8};
  int cum = 0;
  for (int i = 0; i < 8; ++i) {
    cv.s[i] = srcs[i];
    cv.d[i] = dsts[i];
    cv.cum8[i] = cum;
    cum += sz8[i];
  }
  cv.cum8[8] = cum;
  cvt_k<<<2048, 256, 0, stream>>>(cv, cum);

  // 1. transpose features -> f2 (bf16)
  transpose_features_k<<<Bb * 2, 256, 0, stream>>>(features, f2);
  // 2. embedding gather -> inputs[:,:,512:] (bf16)
  gather_embed_k<<<(Bb * Tt * 64 + 255) / 256, 256, 0, stream>>>(
      captions, embed_W, inputs);
  // 3. fv = f2 @ att_fc_v_W^T + b   (3136,512,K=512) -> fp32
  gemm_mfma<512, 4><<<dim3(8, 49), 256, 0, stream>>>(
      f2, 512, att_fc_v_Wb, 512, att_fc_v_b, nullptr, 0, fv, nullptr, 512, 512,
      nullptr);
  // 4. L2-normalize fv rows (fp32 + bf16 copy)
  norm_rows_k<<<(Bb * Ll + 3) / 4, 256, 0, stream>>>(fv, fvb, Bb * Ll);
  // 5. feas0 = feature_0 @ img_embed_W^T + b -> inputs[b,0,:512] (bf16)
  gemm_mfma<2048, 4><<<dim3(8, 1), 256, 0, stream>>>(
      feature_0b, 2048, img_embedb, 2048, img_embed_b, nullptr, 0, nullptr,
      inputs, Tt * 1024, 512, nullptr);
  // 6. att_fea = fv @ att_vw_W^T  (3136,512,512) -> fp32
  gemm_mfma<512, 4><<<dim3(8, 49), 256, 0, stream>>>(
      fvb, 512, att_vw_Wb, 512, nullptr, nullptr, 0, att_fea, nullptr, 512,
      512, nullptr);
  // 7. att_h = we @ att_hw_W^T  (1280,512,K=512) -> fp32
  gemm_mfma<512, 4><<<dim3(8, 20), 256, 0, stream>>>(
      inputs + 512, 1024, att_hw_Wb, 512, nullptr, nullptr, 0, att_h, nullptr,
      512, 512, nullptr);
  // 8. fused attention -> ctx into inputs[b,t+1,:512] (bf16)
  attention_k<<<Bb * 19, 256, 0, stream>>>(att_fea, att_h, att_bias, att_w_W,
                                           fv, inputs);
  // 9. xg = inputs @ W_ih^T + b_ih  (1280,2048,K=1024) -> fp32
  gemm_mfma<1024, 4><<<dim3(32, 20), 256, 0, stream>>>(
      inputs, 1024, W_ihb, 1024, b_ih, nullptr, 0, xg, nullptr, 2048, 2048,
      nullptr);
  // 10. LSTM loop: fused gates+cell per step, h ping-pong, record hseq
  hipMemsetAsync(h0, 0, (size_t)Bb * 512 * 2, stream);
  hipMemsetAsync(c, 0, (size_t)Bb * 512 * 4, stream);
  const ushort* hc = h0;
  ushort* hn = h1;
  for (int t = 0; t < Tt; ++t) {
    lstm_step_k<<<Hh / 16, 256, 0, stream>>>(hc, hn, c, W_hhb, b_hh, xg,
                                             lengths, hseq, t);
    const ushort* tmp = hn;
    hn = (ushort*)hc;
    hc = tmp;
  }
  // 11. batched logits: hseq(1280,512) @ fc_out_W^T + b, (b,t)-mask -> out
  gemm_mfma<512, 8><<<dim3(313, 10), 256, 0, stream>>>(
      hseq, 512, fc_out_Wb, 512, fc_out_b, nullptr, 0, out, nullptr, Vv, Vv,
      lengths);
}